// Round 12
// baseline (284.069 us; speedup 1.0000x reference)
//
#include <hip/hip_runtime.h>
#include <stdint.h>

// spike_seq: (T=1024, B=16384, 2) fp32, values EXACTLY 0.0/1.0.
// Outputs flat: spk_rec (T*B) then mem_rec (T*B), fp32.
//
// R12: row-owning replay. 11 rounds of evidence: any kernel whose per-block
// output footprint is column-sliced (256B-1KB pieces at 64KB stride) caps at
// 1.7-2.5 TB/s CHIP-WIDE regardless of structure; fillBuffer (6.7 TB/s)
// streams contiguous ascending ranges per block. Checkpoint+replay lets
// blocks own ROWS: block (s,q,h) restarts from a dense checkpoint, replays
// <=12 discarded steps, then writes 4 COMPLETE half-rows (8KB-contiguous
// chunks, ascending) — the fillBuffer pattern.
//   K1  compress x -> 2 bits/sample (4 MB ws).
//   K2a scan all t, 1 wave/CU, checkpoint (mem,inh) every IVL steps.
//   K2b replay: 512 blocks x 512 thr (16 neurons/thread, 2 blocks/CU).
// IVL chosen from ws_size: 8 (needs ~21 MB ws, avg 2 discard rows) else
// 16 (needs ~12.5 MB, avg 6 discard rows).
#define T_LEN 1024
#define B_N   16384
#define CW_WORDS (B_N * (T_LEN / 16))   // 1,048,576 words = 4 MiB

// ---------------------------------------------------------------------------
// K1: word (j,n) packs t=16j..16j+15 of neuron n: bit(2k)=x0, bit(2k+1)=x1.
__global__ __launch_bounds__(256) void k1_compress(
    const float* __restrict__ x, unsigned int* __restrict__ cw) {
  const int tid = blockIdx.x * 256 + threadIdx.x;   // 0..524287
  const int pn  = tid & (B_N / 2 - 1);
  const int j   = tid >> 13;
  const float4* xp4 = (const float4*)x;
  unsigned int wA = 0, wB = 0;
#pragma unroll
  for (int k = 0; k < 16; ++k) {
    const float4 v = xp4[(size_t)(16 * j + k) * (B_N / 2) + pn];
    wA |= (v.x != 0.0f ? 1u : 0u) << (2 * k);
    wA |= (v.y != 0.0f ? 1u : 0u) << (2 * k + 1);
    wB |= (v.z != 0.0f ? 1u : 0u) << (2 * k);
    wB |= (v.w != 0.0f ? 1u : 0u) << (2 * k + 1);
  }
  ((uint2*)cw)[(size_t)j * (B_N / 2) + pn] = make_uint2(wA, wB);
}

// ---------------------------------------------------------------------------
// K2a: full scan t=0..1023, 1 thread/neuron (1 wave/CU). Checkpoints:
// ivl8: chk[c] = state after t=8(c+1)-1, c=0..126;
// ivl16: chk[c] = state after t=16(c+1)-1, c=0..62.
__global__ __launch_bounds__(64, 1) void k2a_checkpoint(
    const unsigned int* __restrict__ cw,
    const float* __restrict__ w_exc, const float* __restrict__ w_inh,
    float2* __restrict__ chk, int ivl8) {
#pragma clang fp contract(off)
  const int n = blockIdx.x * 64 + threadIdx.x;
  const float w0 = w_exc[0], w1 = w_exc[1], wi = w_inh[0];
  float mem = 0.0f, inh = 0.0f;
  unsigned int A = cw[n];
  unsigned int Bw = cw[(size_t)1 * B_N + n];
  unsigned int C = cw[(size_t)2 * B_N + n];
  unsigned int D = cw[(size_t)3 * B_N + n];

#define STEP8(W, KB)                                                 \
  _Pragma("unroll") for (int k = (KB); k < (KB) + 8; ++k) {          \
    const float x0 = (float)(((W) >> (2 * k)) & 1u);                 \
    const float x1 = (float)(((W) >> (2 * k + 1)) & 1u);             \
    const float cur_exc = x0 * w0 + x1 * w1;  /* exact ref order */  \
    inh = 0.6f * inh + x0;                                           \
    const float cur = cur_exc + wi * inh;     /* wi=-1 exact */      \
    const float reset = (mem > 1.0f) ? 1.0f : 0.0f;                  \
    mem = 0.9f * mem + cur - reset;           /* reset*1.0==reset */ \
  }
#define WORD(W, JW)                                                  \
  {                                                                  \
    STEP8(W, 0)                                                      \
    if (ivl8) chk[(size_t)(2 * (JW)) * B_N + n] = make_float2(mem, inh); \
    STEP8(W, 8)                                                      \
    if ((JW) <= 62)                                                  \
      chk[(size_t)(ivl8 ? 2 * (JW) + 1 : (JW)) * B_N + n] =          \
          make_float2(mem, inh);                                     \
  }

  for (int j = 0; j < 64; j += 4) {
    unsigned int nA = 0, nB = 0, nC = 0, nD = 0;
    if (j + 4 < 64) {
      nA = cw[(size_t)(j + 4) * B_N + n];
      nB = cw[(size_t)(j + 5) * B_N + n];
      nC = cw[(size_t)(j + 6) * B_N + n];
      nD = cw[(size_t)(j + 7) * B_N + n];
    }
    __builtin_amdgcn_sched_barrier(0);  // prefetch issued before consume
    WORD(A, j) WORD(Bw, j + 1) WORD(C, j + 2) WORD(D, j + 3)
    A = nA; Bw = nB; C = nC; D = nD;
  }
#undef WORD
#undef STEP8
}

// ---------------------------------------------------------------------------
// K2b: row-owning replay. bx = (r<<1)|h; ivl8: q=r&1, s=r>>1 (128 segs);
// ivl16: q=r&3, s=r>>2 (64 segs). Block writes rows tw..tw+3, tw=s*ivl+4q,
// half h (8192 neurons). Thread owns 16 neurons as 4 groups of 4 so each
// float4 store is lane-contiguous: group c = neurons h*8192+c*2048+4*tid..+3.
// Per plane per row the block emits 4 ascending 8KB-contiguous chunks; over
// 4 rows, a linearly-ascending ~32KB front — the fillBuffer pattern.
// All loads (1 cw word + 1 chk float2 per neuron) in the prologue; the main
// loop is store-only (no load-wait can chain behind store acks).
__global__ __launch_bounds__(512, 2) void FMFMNeuronInhib_34033320854098_kernel(
    const unsigned int* __restrict__ cw, const float2* __restrict__ chk,
    const float* __restrict__ w_exc, const float* __restrict__ w_inh,
    float* __restrict__ out, int ivl) {
#pragma clang fp contract(off)
  const int tid = threadIdx.x;
  const int bx  = blockIdx.x;
  const int h   = bx & 1;
  const int r   = bx >> 1;
  const int ivl8 = (ivl == 8);
  const int q = ivl8 ? (r & 1) : (r & 3);
  const int s = ivl8 ? (r >> 1) : (r >> 2);
  const int tseg = s * ivl;
  const int tw   = tseg + 4 * q;     // first written row
  const int j0   = tw >> 4;          // all seg steps live in this cw word
  const int kd0  = tseg & 15;        // seg-start bit
  const int kw0  = tw & 15;          // write-start bit (= kd0 + 4q)

  const float w0 = w_exc[0], w1 = w_exc[1], wi = w_inh[0];
  float* __restrict__ spk_out = out;
  float* __restrict__ mem_out = out + (size_t)T_LEN * B_N;

  // Prologue loads: 4 uint4 (cw) + 8 float4 (chk), all lane-contiguous.
  uint4 wv[4];
  float mem[4][4], inh[4][4];
#pragma unroll
  for (int c = 0; c < 4; ++c) {
    const int nc = h * 8192 + c * 2048 + 4 * tid;
    wv[c] = *(const uint4*)&cw[(size_t)j0 * B_N + nc];
    if (s > 0) {
      const float4* cp = (const float4*)&chk[(size_t)(s - 1) * B_N + nc];
      const float4 a = cp[0], b = cp[1];
      mem[c][0] = a.x; inh[c][0] = a.y; mem[c][1] = a.z; inh[c][1] = a.w;
      mem[c][2] = b.x; inh[c][2] = b.y; mem[c][3] = b.z; inh[c][3] = b.w;
    } else {
#pragma unroll
      for (int m = 0; m < 4; ++m) { mem[c][m] = 0.0f; inh[c][m] = 0.0f; }
    }
  }

#define NSTEP(c, m, W)                                              \
  {                                                                 \
    const float x0 = (float)(((W) >> (2 * k)) & 1u);                \
    const float x1 = (float)(((W) >> (2 * k + 1)) & 1u);            \
    const float cur_exc = x0 * w0 + x1 * w1;                        \
    inh[c][m] = 0.6f * inh[c][m] + x0;                              \
    const float cur = cur_exc + wi * inh[c][m];                     \
    const float reset = (mem[c][m] > 1.0f) ? 1.0f : 0.0f;           \
    mem[c][m] = 0.9f * mem[c][m] + cur - reset;                     \
  }

  // Discard-replay: 0..12 steps (runtime trip; bodies fully unrolled).
  for (int k = kd0; k < kw0; ++k) {
#pragma unroll
    for (int c = 0; c < 4; ++c) {
      NSTEP(c, 0, wv[c].x) NSTEP(c, 1, wv[c].y)
      NSTEP(c, 2, wv[c].z) NSTEP(c, 3, wv[c].w)
    }
  }
  // Write phase: 4 rows, store-only traffic.
  for (int k = kw0; k < kw0 + 4; ++k) {
    const int t = (j0 << 4) + k;
#pragma unroll
    for (int c = 0; c < 4; ++c) {
      NSTEP(c, 0, wv[c].x) NSTEP(c, 1, wv[c].y)
      NSTEP(c, 2, wv[c].z) NSTEP(c, 3, wv[c].w)
      float4 sv, mv;
      sv.x = (mem[c][0] > 1.0f) ? 1.0f : 0.0f; mv.x = mem[c][0];
      sv.y = (mem[c][1] > 1.0f) ? 1.0f : 0.0f; mv.y = mem[c][1];
      sv.z = (mem[c][2] > 1.0f) ? 1.0f : 0.0f; mv.z = mem[c][2];
      sv.w = (mem[c][3] > 1.0f) ? 1.0f : 0.0f; mv.w = mem[c][3];
      const size_t base = (size_t)t * B_N + h * 8192 + c * 2048 + 4 * tid;
      *(float4*)&spk_out[base] = sv;   // 1KB/wave-instr, ascending chunks
      *(float4*)&mem_out[base] = mv;
    }
  }
#undef NSTEP
}

extern "C" void kernel_launch(void* const* d_in, const int* in_sizes, int n_in,
                              void* d_out, int out_size, void* d_ws, size_t ws_size,
                              hipStream_t stream) {
  const float* x     = (const float*)d_in[0];
  const float* w_exc = (const float*)d_in[1];
  const float* w_inh = (const float*)d_in[2];
  float* out = (float*)d_out;
  unsigned int* cw = (unsigned int*)d_ws;                        // 4 MiB
  float2* chk = (float2*)((char*)d_ws + ((size_t)CW_WORDS * 4)); // after cw

  const size_t need8 = (size_t)CW_WORDS * 4 + (size_t)127 * B_N * 8;  // ~21 MB
  const int ivl = (ws_size == 0 || ws_size >= need8) ? 8 : 16;
  // (ivl=16 needs ~12.5 MB; prior rounds proved >=5 MB of usable ws.)

  hipLaunchKernelGGL(k1_compress, dim3(CW_WORDS / 2 / 256), dim3(256), 0,
                     stream, x, cw);
  hipLaunchKernelGGL(k2a_checkpoint, dim3(B_N / 64), dim3(64), 0, stream,
                     cw, w_exc, w_inh, chk, ivl == 8 ? 1 : 0);
  hipLaunchKernelGGL(FMFMNeuronInhib_34033320854098_kernel, dim3(512),
                     dim3(512), 0, stream, cw, chk, w_exc, w_inh, out, ivl);
}

// Round 13
// 230.169 us; speedup vs baseline: 1.2342x; 1.2342x over previous
//
#include <hip/hip_runtime.h>

// spike_seq: (T=1024, B=16384, 2) fp32; w_exc={0.7,1.0}; w_inh=-1.0.
// Outputs flat: spk_rec (T*B) then mem_rec (T*B), fp32.
//
// FINAL (session champion, R7 = best of 13 benches: 79.6us dispatch).
// 12 structurally-distinct variants established: this op's T-major
// 3-stream pattern pins at ~2.5 TB/s chip-wide regardless of prefetch
// depth (R2/R6), vmcnt-domain splits (R4-R6), store width (R7), per-block
// footprint/CU-count (R8), store-only decomposition (R9), occupancy (R12),
// or per-block contiguity (R12 checkpoint+replay). R2/R4/R7 all sit at
// 79.6-82.4us => plateau; R7 kept as champion.
//
// Structure: 4 waves/CU. w0 compute (pure VALU+LDS), w1 loader
// (global_load_lds dwordx4, counted vmcnt, 3 phases ahead), w2/w3 storers
// (LDS-transposed dwordx4 stores, fire-and-forget in their own vmcnt
// domains). Raw s_barrier + lgkmcnt waits only; the loader's vmcnt waits
// are counted (never 0 mid-loop).
#define T_LEN 1024
#define B_N   16384
#define PH    16              // timesteps per phase
#define NPH   (T_LEN / PH)    // 64
#define RIN   4               // IN ring depth (32 KiB)

__shared__ __align__(16) float2 IN_lds[RIN][PH][64];  // 32 KiB input ring
__shared__ __align__(16) float  SPK_lds[2][PH][64];   // 8 KiB
__shared__ __align__(16) float  MEM_lds[2][PH][64];   // 8 KiB

static __device__ __forceinline__ void block_barrier() {
  asm volatile("" ::: "memory");   // compiler fence: no mem-op motion
  __builtin_amdgcn_s_barrier();
  asm volatile("" ::: "memory");
}

__global__ __launch_bounds__(256, 1) void FMFMNeuronInhib_34033320854098_kernel(
    const float* __restrict__ x,      // (T, B, 2)
    const float* __restrict__ w_exc,  // {0.7, 1.0}
    const float* __restrict__ w_inh,  // {-1.0}
    float* __restrict__ out) {
#pragma clang fp contract(off)
  const int lane = threadIdx.x & 63;
  const int wid  = threadIdx.x >> 6;   // 0=compute 1=loader 2=spk-st 3=mem-st
  const int nb0  = blockIdx.x * 64;    // this block's first neuron

  float* __restrict__ spk_out = out;
  float* __restrict__ mem_out = out + (size_t)T_LEN * B_N;

  if (wid == 1) {
    // ---------------- loader ----------------
    // Phase p: rows t=p*PH..p*PH+15, 512B/row. One dwordx4 global_load_lds
    // covers 2 rows (1KB): lanes 0-31 row 2j, lanes 32-63 row 2j+1. LDS dest
    // is wave-uniform base + lane*16 (linear, matches [PH][64]float2 rows).
    const int half = lane >> 5;
    const int l32  = lane & 31;
    auto issue_phase = [&](int q) {
#pragma unroll
      for (int j = 0; j < 8; ++j) {
        const int t = q * PH + 2 * j + half;
        const float* src = x + ((size_t)t * B_N + nb0) * 2 + (size_t)l32 * 4;
        __builtin_amdgcn_global_load_lds(
            (const __attribute__((address_space(1))) void*)src,
            (__attribute__((address_space(3))) void*)&IN_lds[q & 3][2 * j][0],
            16, 0, 0);
      }
    };
    issue_phase(0); issue_phase(1); issue_phase(2);   // 24 ops in flight
    asm volatile("s_waitcnt vmcnt(16)" ::: "memory"); // phase 0 landed
    block_barrier();
    for (int p = 0; p < NPH; ++p) {
      if (p + 3 < NPH) issue_phase(p + 3);  // slot (p-1)&3: freed at barrier p-1
      // Guarantee phase p+1 landed before barrier p; keep younger phases
      // (p+2, p+3: 16 ops) in flight — counted wait, never 0 mid-loop.
      if (p <= NPH - 4)      asm volatile("s_waitcnt vmcnt(16)" ::: "memory");
      else if (p == NPH - 3) asm volatile("s_waitcnt vmcnt(8)"  ::: "memory");
      else                   asm volatile("s_waitcnt vmcnt(0)"  ::: "memory");
      block_barrier();
    }
  } else if (wid == 0) {
    // ---------------- compute: pure VALU + LDS ----------------
    const float w0 = w_exc[0];
    const float w1 = w_exc[1];
    const float wi = w_inh[0];
    float mem = 0.0f, inh = 0.0f;
    block_barrier();                                  // prologue barrier
    for (int p = 0; p < NPH; ++p) {
      float2 xv[PH];
#pragma unroll
      for (int u = 0; u < PH; ++u) xv[u] = IN_lds[p & 3][u][lane];
#pragma unroll
      for (int u = 0; u < PH; ++u) {
        const float x0 = xv[u].x;
        const float x1 = xv[u].y;
        // Exact reference op order; no FMA contraction (1 ulp flips a spike).
        const float cur_exc = x0 * w0 + x1 * w1;   // x @ w_exc^T
        inh = 0.6f * inh + x0;                     // inh decay + feed
        const float cur = cur_exc + wi * inh;      // wi = -1.0 exact
        // (mem-1>0) == (mem>1) exactly; reset*1.0f == reset.
        const float reset = (mem > 1.0f) ? 1.0f : 0.0f;
        mem = 0.9f * mem + cur - reset;
        const float spk = (mem > 1.0f) ? 1.0f : 0.0f;
        SPK_lds[p & 1][u][lane] = spk;             // separate planes so the
        MEM_lds[p & 1][u][lane] = mem;             // storer can read float4
      }
      // All ds_reads (IN slot reusable) and ds_writes (visible to storers)
      // retired before the barrier.
      asm volatile("s_waitcnt lgkmcnt(0)" ::: "memory");
      block_barrier();
    }
  } else {
    // ---------------- storers: packed dwordx4, one plane each ----------------
    const float* plane = (wid == 2) ? &SPK_lds[0][0][0] : &MEM_lds[0][0][0];
    float* gout        = (wid == 2) ? spk_out : mem_out;
    const int r  = lane >> 4;          // row within group of 4
    const int n0 = (lane & 15) * 4;    // 4 adjacent neurons
    auto drain = [&](int p) {
      const int tb   = p * PH;
      const int slot = p & 1;
#pragma unroll
      for (int j = 0; j < 4; ++j) {    // 4 instr cover 16 rows
        const int row = 4 * j + r;
        const float4 v =
            *(const float4*)(plane + ((size_t)slot * PH + row) * 64 + n0);
        *(float4*)&gout[(size_t)(tb + row) * B_N + nb0 + n0] = v;
      }
      // ds_reads retired -> compute may overwrite this slot next phase.
      // Global stores fire-and-forget in this wave's own vmcnt domain.
      asm volatile("s_waitcnt lgkmcnt(0)" ::: "memory");
    };
    block_barrier();                                  // prologue barrier
    for (int p = 0; p < NPH; ++p) {
      if (p >= 1) drain(p - 1);  // reads slot (p-1)&1 while compute writes p&1
      block_barrier();
    }
    drain(NPH - 1);  // final phase, ordered by the last in-loop barrier
  }
}

extern "C" void kernel_launch(void* const* d_in, const int* in_sizes, int n_in,
                              void* d_out, int out_size, void* d_ws, size_t ws_size,
                              hipStream_t stream) {
  const float* x     = (const float*)d_in[0];  // spike_seq, T*B*2 floats
  const float* w_exc = (const float*)d_in[1];  // 2 floats
  const float* w_inh = (const float*)d_in[2];  // 1 float
  float* out = (float*)d_out;                  // spk_rec ++ mem_rec

  dim3 grid(B_N / 64);   // 256 blocks -> 1 block (4 waves, 1/SIMD) per CU
  dim3 block(256);       // w0 compute, w1 loader, w2 spk-storer, w3 mem-storer
  hipLaunchKernelGGL(FMFMNeuronInhib_34033320854098_kernel, grid, block, 0, stream,
                     x, w_exc, w_inh, out);
}